// Round 1
// baseline (1927.344 us; speedup 1.0000x reference)
//
#include <hip/hip_runtime.h>
#include <hip/hip_bf16.h>

// ---------------------------------------------------------------------------
// GAT link-prediction forward: 3 GATConv layers on a fixed graph.
// Layer l: s = h @ Wl;  alpha_src/dst = <s, a_vec> per head;
//          e = leakyrelu(as[src]+ad[dst]); softmax over in-edges of dst;
//          out[dst] = sum alpha * s[src]; (+bias, activation)
// Layers 0/1: concat heads (128 cols), ELU / ReLU. Layer 2: head-mean, ReLU.
// ---------------------------------------------------------------------------

// Detect whether edge_index arrived as int64 (high words all zero) or int32.
__global__ void detect_i64(const unsigned* __restrict__ ei, int* __restrict__ flag) {
    if (threadIdx.x == 0 && blockIdx.x == 0) {
        int allz = 1;
        for (int i = 0; i < 128; ++i)
            if (ei[2 * i + 1] != 0u) { allz = 0; break; }
        *flag = allz;
    }
}

__global__ void gat_count(const void* __restrict__ ei, const int* __restrict__ flag,
                          int nE, int nN, int* __restrict__ cnt) {
    const int i64 = *flag;
    const long long total = (long long)nE + nN;
    const long long stride = (long long)gridDim.x * blockDim.x;
    for (long long i = (long long)blockIdx.x * blockDim.x + threadIdx.x; i < total; i += stride) {
        int d;
        if (i < nE) d = i64 ? (int)((const long long*)ei)[nE + i] : ((const int*)ei)[nE + i];
        else        d = (int)(i - nE);
        atomicAdd(&cnt[d], 1);
    }
}

// Single-wave exclusive scan over counts -> row_ptr, and a cursor copy.
__global__ void gat_scan(const int* __restrict__ cnt, int* __restrict__ rowp,
                         int* __restrict__ cur, int n) {
    const int lane = threadIdx.x;  // blockDim = 64, grid = 1
    int carry = 0;
    for (int base = 0; base < n; base += 64) {
        const int i = base + lane;
        int v = (i < n) ? cnt[i] : 0;
        int incl = v;
        #pragma unroll
        for (int off = 1; off < 64; off <<= 1) {
            const int t = __shfl_up(incl, off);
            if (lane >= off) incl += t;
        }
        if (i < n) { const int e = carry + incl - v; rowp[i] = e; cur[i] = e; }
        carry += __shfl(incl, 63);
    }
    if (lane == 0) rowp[n] = carry;
}

__global__ void gat_scatter(const void* __restrict__ ei, const int* __restrict__ flag,
                            int nE, int nN, int* __restrict__ cur, int* __restrict__ csr) {
    const int i64 = *flag;
    const long long total = (long long)nE + nN;
    const long long stride = (long long)gridDim.x * blockDim.x;
    for (long long i = (long long)blockIdx.x * blockDim.x + threadIdx.x; i < total; i += stride) {
        int s, d;
        if (i < nE) {
            if (i64) { s = (int)((const long long*)ei)[i]; d = (int)((const long long*)ei)[nE + i]; }
            else     { s = ((const int*)ei)[i];            d = ((const int*)ei)[nE + i]; }
        } else { s = d = (int)(i - nE); }
        const int pos = atomicAdd(&cur[d], 1);
        csr[pos] = s;
    }
}

// s = Xin @ W (50000x128 @ 128x128 f32), W staged in LDS (64KB).
// One wave computes 2 rows; lane l owns output cols 2l, 2l+1.
// Epilogue: alpha_src/alpha_dst per head (a-vector flat index == global col).
__global__ __launch_bounds__(256) void gemm_alpha(
    const float* __restrict__ Xin, const float* __restrict__ W,
    const float* __restrict__ avs, const float* __restrict__ avd,
    float* __restrict__ S, float* __restrict__ as_, float* __restrict__ ad_, int n) {
    __shared__ float Wl[128 * 128];
    for (int i = threadIdx.x; i < 128 * 128 / 4; i += 256)
        ((float4*)Wl)[i] = ((const float4*)W)[i];
    __syncthreads();
    const int lane = threadIdx.x & 63;
    const int wv = threadIdx.x >> 6;
    const int nwaves = gridDim.x * 4;
    const int npairs = (n + 1) >> 1;
    for (int pr = blockIdx.x * 4 + wv; pr < npairs; pr += nwaves) {
        const int r0 = 2 * pr, r1 = 2 * pr + 1;
        const float2 x0 = *(const float2*)(Xin + (size_t)r0 * 128 + 2 * lane);
        const float2 x1 = (r1 < n) ? *(const float2*)(Xin + (size_t)r1 * 128 + 2 * lane)
                                   : make_float2(0.f, 0.f);
        float2 acc0 = make_float2(0.f, 0.f), acc1 = make_float2(0.f, 0.f);
        #pragma unroll
        for (int k = 0; k < 128; ++k) {
            const float2 w = *(const float2*)(Wl + k * 128 + 2 * lane);
            const float xk0 = __shfl((k & 1) ? x0.y : x0.x, k >> 1);
            const float xk1 = __shfl((k & 1) ? x1.y : x1.x, k >> 1);
            acc0.x = fmaf(xk0, w.x, acc0.x); acc0.y = fmaf(xk0, w.y, acc0.y);
            acc1.x = fmaf(xk1, w.x, acc1.x); acc1.y = fmaf(xk1, w.y, acc1.y);
        }
        *(float2*)(S + (size_t)r0 * 128 + 2 * lane) = acc0;
        if (r1 < n) *(float2*)(S + (size_t)r1 * 128 + 2 * lane) = acc1;
        const float2 av = *(const float2*)(avs + 2 * lane);
        const float2 dv = *(const float2*)(avd + 2 * lane);
        float ps0 = acc0.x * av.x + acc0.y * av.y;
        float pd0 = acc0.x * dv.x + acc0.y * dv.y;
        float ps1 = acc1.x * av.x + acc1.y * av.y;
        float pd1 = acc1.x * dv.x + acc1.y * dv.y;
        #pragma unroll
        for (int off = 16; off; off >>= 1) {  // reduce within 32-lane (per-head) halves
            ps0 += __shfl_xor(ps0, off); pd0 += __shfl_xor(pd0, off);
            ps1 += __shfl_xor(ps1, off); pd1 += __shfl_xor(pd1, off);
        }
        if ((lane & 31) == 0) {
            const int h = lane >> 5;
            as_[2 * r0 + h] = ps0; ad_[2 * r0 + h] = pd0;
            if (r1 < n) { as_[2 * r1 + h] = ps1; ad_[2 * r1 + h] = pd1; }
        }
    }
}

// One wave per destination node: exact segment softmax (2 scalar passes over
// in-edges) + attention-weighted gather of s rows. mode 0=ELU(concat),
// 1=ReLU(concat), 2=ReLU(head-mean).
__global__ __launch_bounds__(256) void gat_aggregate(
    const float* __restrict__ S, const float* __restrict__ as_, const float* __restrict__ ad_,
    const int* __restrict__ rowp, const int* __restrict__ csr,
    const float* __restrict__ bias, float* __restrict__ out, int n, int mode) {
    const int lane = threadIdx.x & 63;
    const int d = (blockIdx.x * blockDim.x + threadIdx.x) >> 6;
    if (d >= n) return;
    const int beg = rowp[d], end = rowp[d + 1];
    const int h = lane >> 5;
    const float2 adv = *(const float2*)(ad_ + 2 * d);
    // pass 1: per-head max of e = leakyrelu(as[src] + ad[dst])
    float m0 = -1e30f, m1 = -1e30f;
    for (int i = beg + lane; i < end; i += 64) {
        const int s = csr[i];
        const float2 asv = *(const float2*)(as_ + 2 * s);
        float e0 = asv.x + adv.x; e0 = e0 > 0.f ? e0 : 0.2f * e0;
        float e1 = asv.y + adv.y; e1 = e1 > 0.f ? e1 : 0.2f * e1;
        m0 = fmaxf(m0, e0); m1 = fmaxf(m1, e1);
    }
    #pragma unroll
    for (int off = 32; off; off >>= 1) {
        m0 = fmaxf(m0, __shfl_xor(m0, off));
        m1 = fmaxf(m1, __shfl_xor(m1, off));
    }
    // pass 2: per-head denom
    float s0 = 0.f, s1 = 0.f;
    for (int i = beg + lane; i < end; i += 64) {
        const int s = csr[i];
        const float2 asv = *(const float2*)(as_ + 2 * s);
        float e0 = asv.x + adv.x; e0 = e0 > 0.f ? e0 : 0.2f * e0;
        float e1 = asv.y + adv.y; e1 = e1 > 0.f ? e1 : 0.2f * e1;
        s0 += __expf(e0 - m0); s1 += __expf(e1 - m1);
    }
    #pragma unroll
    for (int off = 32; off; off >>= 1) {
        s0 += __shfl_xor(s0, off);
        s1 += __shfl_xor(s1, off);
    }
    const float mh   = h ? m1 : m0;
    const float rinv = 1.f / (h ? s1 : s0);
    const float adh  = h ? adv.y : adv.x;
    // pass 3: gather + accumulate. lane l holds cols 2l,2l+1 (head = l>>5).
    float2 acc = make_float2(0.f, 0.f);
    int s_next = (beg < end) ? csr[beg] : 0;
    for (int i = beg; i < end; ++i) {
        const int s = s_next;
        if (i + 1 < end) s_next = csr[i + 1];
        const float2 asv = *(const float2*)(as_ + 2 * s);
        const float a = h ? asv.y : asv.x;
        float e = a + adh; e = e > 0.f ? e : 0.2f * e;
        const float alpha = __expf(e - mh) * rinv;
        const float2 v = *(const float2*)(S + (size_t)s * 128 + 2 * lane);
        acc.x = fmaf(alpha, v.x, acc.x);
        acc.y = fmaf(alpha, v.y, acc.y);
    }
    if (mode == 2) {
        float ox = acc.x + __shfl_xor(acc.x, 32);
        float oy = acc.y + __shfl_xor(acc.y, 32);
        if (lane < 32) {
            ox = 0.5f * ox + bias[2 * lane];
            oy = 0.5f * oy + bias[2 * lane + 1];
            *(float2*)(out + (size_t)d * 64 + 2 * lane) =
                make_float2(fmaxf(ox, 0.f), fmaxf(oy, 0.f));
        }
    } else {
        float ox = acc.x + bias[2 * lane];
        float oy = acc.y + bias[2 * lane + 1];
        if (mode == 0) { ox = ox > 0.f ? ox : expm1f(ox); oy = oy > 0.f ? oy : expm1f(oy); }
        else           { ox = fmaxf(ox, 0.f);             oy = fmaxf(oy, 0.f); }
        *(float2*)(out + (size_t)d * 128 + 2 * lane) = make_float2(ox, oy);
    }
}

extern "C" void kernel_launch(void* const* d_in, const int* in_sizes, int n_in,
                              void* d_out, int out_size, void* d_ws, size_t ws_size,
                              hipStream_t stream) {
    const float* X   = (const float*)d_in[0];
    const void*  EI  = d_in[1];
    const float* W0  = (const float*)d_in[2];
    const float* as0 = (const float*)d_in[3];
    const float* ad0 = (const float*)d_in[4];
    const float* b0  = (const float*)d_in[5];
    const float* W1  = (const float*)d_in[6];
    const float* as1 = (const float*)d_in[7];
    const float* ad1 = (const float*)d_in[8];
    const float* b1  = (const float*)d_in[9];
    const float* W2  = (const float*)d_in[10];
    const float* as2 = (const float*)d_in[11];
    const float* ad2 = (const float*)d_in[12];
    const float* b2  = (const float*)d_in[13];

    const int N  = in_sizes[0] / 128;   // 50000
    const int E  = in_sizes[1] / 2;     // 1600000
    const int ET = E + N;               // + self loops

    char* p = (char*)d_ws;
    size_t used = 0;
    auto alloc = [&](size_t bytes) -> void* {
        void* r = p + used;
        used += (bytes + 255) & ~(size_t)255;
        return r;
    };
    float* S    = (float*)alloc((size_t)N * 128 * 4);
    float* H0   = (float*)alloc((size_t)N * 128 * 4);
    float* H1   = (float*)alloc((size_t)N * 128 * 4);
    int*   csr  = (int*)alloc((size_t)ET * 4);
    int*   rowp = (int*)alloc((size_t)(N + 1) * 4);
    int*   cur  = (int*)alloc((size_t)N * 4);
    int*   cnt  = (int*)alloc((size_t)N * 4);
    float* asb  = (float*)alloc((size_t)N * 2 * 4);
    float* adb  = (float*)alloc((size_t)N * 2 * 4);
    int*   flag = (int*)alloc(256);
    if (used > ws_size) return;  // fail loudly (validation will catch)

    hipMemsetAsync(cnt, 0, (size_t)N * 4, stream);
    detect_i64<<<1, 64, 0, stream>>>((const unsigned*)EI, flag);
    gat_count<<<2048, 256, 0, stream>>>(EI, flag, E, N, cnt);
    gat_scan<<<1, 64, 0, stream>>>(cnt, rowp, cur, N);
    gat_scatter<<<2048, 256, 0, stream>>>(EI, flag, E, N, cur, csr);

    const int gemm_blocks = (((N + 1) / 2) + 3) / 4;
    const int agg_blocks  = (N + 3) / 4;

    // layer 0: GATConv(128 -> 64, H=2, concat) + ELU
    gemm_alpha<<<gemm_blocks, 256, 0, stream>>>(X, W0, as0, ad0, S, asb, adb, N);
    gat_aggregate<<<agg_blocks, 256, 0, stream>>>(S, asb, adb, rowp, csr, b0, H0, N, 0);
    // layer 1: GATConv(128 -> 64, H=2, concat) + ReLU
    gemm_alpha<<<gemm_blocks, 256, 0, stream>>>(H0, W1, as1, ad1, S, asb, adb, N);
    gat_aggregate<<<agg_blocks, 256, 0, stream>>>(S, asb, adb, rowp, csr, b1, H1, N, 1);
    // layer 2: GATConvMean(128 -> 64, H=2, mean) + ReLU
    gemm_alpha<<<gemm_blocks, 256, 0, stream>>>(H1, W2, as2, ad2, S, asb, adb, N);
    gat_aggregate<<<agg_blocks, 256, 0, stream>>>(S, asb, adb, rowp, csr, b2, (float*)d_out, N, 2);
}

// Round 2
// 1548.456 us; speedup vs baseline: 1.2447x; 1.2447x over previous
//
#include <hip/hip_runtime.h>
#include <hip/hip_bf16.h>

// ---------------------------------------------------------------------------
// GAT link-prediction forward: 3 GATConv layers on a fixed graph.
// Layer l: s = h @ Wl;  alpha_src/dst = <s, a_vec> per head;
//          e = leakyrelu(as[src]+ad[dst]); softmax over in-edges of dst;
//          out[dst] = sum alpha * s[src]; (+bias, activation)
// Layers 0/1: concat heads (128 cols), ELU / ReLU. Layer 2: head-mean, ReLU.
// R1: replaced single-wave 385us serial scan with 3-stage hierarchical scan.
// ---------------------------------------------------------------------------

#define SCAN_BLOCK 256

// Detect whether edge_index arrived as int64 (high words all zero) or int32.
__global__ void detect_i64(const unsigned* __restrict__ ei, int* __restrict__ flag) {
    if (threadIdx.x == 0 && blockIdx.x == 0) {
        int allz = 1;
        for (int i = 0; i < 128; ++i)
            if (ei[2 * i + 1] != 0u) { allz = 0; break; }
        *flag = allz;
    }
}

__global__ void gat_count(const void* __restrict__ ei, const int* __restrict__ flag,
                          int nE, int nN, int* __restrict__ cnt) {
    const int i64 = *flag;
    const long long total = (long long)nE + nN;
    const long long stride = (long long)gridDim.x * blockDim.x;
    for (long long i = (long long)blockIdx.x * blockDim.x + threadIdx.x; i < total; i += stride) {
        int d;
        if (i < nE) d = i64 ? (int)((const long long*)ei)[nE + i] : ((const int*)ei)[nE + i];
        else        d = (int)(i - nE);
        atomicAdd(&cnt[d], 1);
    }
}

// Stage 1: per-block (256-element) inclusive scan + block totals.
__global__ __launch_bounds__(SCAN_BLOCK) void scan_stage1(
    const int* __restrict__ cnt, int* __restrict__ partial, int* __restrict__ bsum, int n) {
    __shared__ int tmp[SCAN_BLOCK];
    const int i = blockIdx.x * SCAN_BLOCK + threadIdx.x;
    const int v = (i < n) ? cnt[i] : 0;
    tmp[threadIdx.x] = v;
    __syncthreads();
    #pragma unroll
    for (int off = 1; off < SCAN_BLOCK; off <<= 1) {
        const int t = (threadIdx.x >= off) ? tmp[threadIdx.x - off] : 0;
        __syncthreads();
        tmp[threadIdx.x] += t;
        __syncthreads();
    }
    if (i < n) partial[i] = tmp[threadIdx.x];
    if (threadIdx.x == SCAN_BLOCK - 1) bsum[blockIdx.x] = tmp[threadIdx.x];
}

// Stage 2: one wave exclusive-scans the block sums in place; writes rowp[n].
__global__ void scan_stage2(int* __restrict__ bsum, int nb, int* __restrict__ rowp, int n) {
    const int lane = threadIdx.x;  // blockDim = 64, grid = 1
    int carry = 0;
    for (int base = 0; base < nb; base += 64) {
        const int i = base + lane;
        const int v = (i < nb) ? bsum[i] : 0;
        int incl = v;
        #pragma unroll
        for (int off = 1; off < 64; off <<= 1) {
            const int t = __shfl_up(incl, off);
            if (lane >= off) incl += t;
        }
        if (i < nb) bsum[i] = carry + incl - v;  // exclusive
        carry += __shfl(incl, 63);
    }
    if (lane == 0) rowp[n] = carry;
}

// Stage 3: rowp[i] = bsumEx[block] + (inclusive - v)  (exclusive global scan).
__global__ __launch_bounds__(SCAN_BLOCK) void scan_stage3(
    const int* __restrict__ partial, const int* __restrict__ cnt, const int* __restrict__ bsum,
    int* __restrict__ rowp, int* __restrict__ cur, int n) {
    const int i = blockIdx.x * SCAN_BLOCK + threadIdx.x;
    if (i < n) {
        const int e = bsum[i >> 8] + partial[i] - cnt[i];
        rowp[i] = e;
        cur[i] = e;
    }
}

__global__ void gat_scatter(const void* __restrict__ ei, const int* __restrict__ flag,
                            int nE, int nN, int* __restrict__ cur, int* __restrict__ csr) {
    const int i64 = *flag;
    const long long total = (long long)nE + nN;
    const long long stride = (long long)gridDim.x * blockDim.x;
    for (long long i = (long long)blockIdx.x * blockDim.x + threadIdx.x; i < total; i += stride) {
        int s, d;
        if (i < nE) {
            if (i64) { s = (int)((const long long*)ei)[i]; d = (int)((const long long*)ei)[nE + i]; }
            else     { s = ((const int*)ei)[i];            d = ((const int*)ei)[nE + i]; }
        } else { s = d = (int)(i - nE); }
        const int pos = atomicAdd(&cur[d], 1);
        csr[pos] = s;
    }
}

// s = Xin @ W (50000x128 @ 128x128 f32), W staged in LDS (64KB).
// One wave computes 2 rows; lane l owns output cols 2l, 2l+1.
// Epilogue: alpha_src/alpha_dst per head (a-vector flat index == global col).
__global__ __launch_bounds__(256) void gemm_alpha(
    const float* __restrict__ Xin, const float* __restrict__ W,
    const float* __restrict__ avs, const float* __restrict__ avd,
    float* __restrict__ S, float* __restrict__ as_, float* __restrict__ ad_, int n) {
    __shared__ float Wl[128 * 128];
    for (int i = threadIdx.x; i < 128 * 128 / 4; i += 256)
        ((float4*)Wl)[i] = ((const float4*)W)[i];
    __syncthreads();
    const int lane = threadIdx.x & 63;
    const int wv = threadIdx.x >> 6;
    const int nwaves = gridDim.x * 4;
    const int npairs = (n + 1) >> 1;
    for (int pr = blockIdx.x * 4 + wv; pr < npairs; pr += nwaves) {
        const int r0 = 2 * pr, r1 = 2 * pr + 1;
        const float2 x0 = *(const float2*)(Xin + (size_t)r0 * 128 + 2 * lane);
        const float2 x1 = (r1 < n) ? *(const float2*)(Xin + (size_t)r1 * 128 + 2 * lane)
                                   : make_float2(0.f, 0.f);
        float2 acc0 = make_float2(0.f, 0.f), acc1 = make_float2(0.f, 0.f);
        #pragma unroll
        for (int k = 0; k < 128; ++k) {
            const float2 w = *(const float2*)(Wl + k * 128 + 2 * lane);
            const float xk0 = __shfl((k & 1) ? x0.y : x0.x, k >> 1);
            const float xk1 = __shfl((k & 1) ? x1.y : x1.x, k >> 1);
            acc0.x = fmaf(xk0, w.x, acc0.x); acc0.y = fmaf(xk0, w.y, acc0.y);
            acc1.x = fmaf(xk1, w.x, acc1.x); acc1.y = fmaf(xk1, w.y, acc1.y);
        }
        *(float2*)(S + (size_t)r0 * 128 + 2 * lane) = acc0;
        if (r1 < n) *(float2*)(S + (size_t)r1 * 128 + 2 * lane) = acc1;
        const float2 av = *(const float2*)(avs + 2 * lane);
        const float2 dv = *(const float2*)(avd + 2 * lane);
        float ps0 = acc0.x * av.x + acc0.y * av.y;
        float pd0 = acc0.x * dv.x + acc0.y * dv.y;
        float ps1 = acc1.x * av.x + acc1.y * av.y;
        float pd1 = acc1.x * dv.x + acc1.y * dv.y;
        #pragma unroll
        for (int off = 16; off; off >>= 1) {  // reduce within 32-lane (per-head) halves
            ps0 += __shfl_xor(ps0, off); pd0 += __shfl_xor(pd0, off);
            ps1 += __shfl_xor(ps1, off); pd1 += __shfl_xor(pd1, off);
        }
        if ((lane & 31) == 0) {
            const int h = lane >> 5;
            as_[2 * r0 + h] = ps0; ad_[2 * r0 + h] = pd0;
            if (r1 < n) { as_[2 * r1 + h] = ps1; ad_[2 * r1 + h] = pd1; }
        }
    }
}

// One wave per destination node: exact segment softmax (2 scalar passes over
// in-edges) + attention-weighted gather of s rows. mode 0=ELU(concat),
// 1=ReLU(concat), 2=ReLU(head-mean).
__global__ __launch_bounds__(256) void gat_aggregate(
    const float* __restrict__ S, const float* __restrict__ as_, const float* __restrict__ ad_,
    const int* __restrict__ rowp, const int* __restrict__ csr,
    const float* __restrict__ bias, float* __restrict__ out, int n, int mode) {
    const int lane = threadIdx.x & 63;
    const int d = (blockIdx.x * blockDim.x + threadIdx.x) >> 6;
    if (d >= n) return;
    const int beg = rowp[d], end = rowp[d + 1];
    const int h = lane >> 5;
    const float2 adv = *(const float2*)(ad_ + 2 * d);
    // pass 1: per-head max of e = leakyrelu(as[src] + ad[dst])
    float m0 = -1e30f, m1 = -1e30f;
    for (int i = beg + lane; i < end; i += 64) {
        const int s = csr[i];
        const float2 asv = *(const float2*)(as_ + 2 * s);
        float e0 = asv.x + adv.x; e0 = e0 > 0.f ? e0 : 0.2f * e0;
        float e1 = asv.y + adv.y; e1 = e1 > 0.f ? e1 : 0.2f * e1;
        m0 = fmaxf(m0, e0); m1 = fmaxf(m1, e1);
    }
    #pragma unroll
    for (int off = 32; off; off >>= 1) {
        m0 = fmaxf(m0, __shfl_xor(m0, off));
        m1 = fmaxf(m1, __shfl_xor(m1, off));
    }
    // pass 2: per-head denom
    float s0 = 0.f, s1 = 0.f;
    for (int i = beg + lane; i < end; i += 64) {
        const int s = csr[i];
        const float2 asv = *(const float2*)(as_ + 2 * s);
        float e0 = asv.x + adv.x; e0 = e0 > 0.f ? e0 : 0.2f * e0;
        float e1 = asv.y + adv.y; e1 = e1 > 0.f ? e1 : 0.2f * e1;
        s0 += __expf(e0 - m0); s1 += __expf(e1 - m1);
    }
    #pragma unroll
    for (int off = 32; off; off >>= 1) {
        s0 += __shfl_xor(s0, off);
        s1 += __shfl_xor(s1, off);
    }
    const float mh   = h ? m1 : m0;
    const float rinv = 1.f / (h ? s1 : s0);
    const float adh  = h ? adv.y : adv.x;
    // pass 3: gather + accumulate. lane l holds cols 2l,2l+1 (head = l>>5).
    float2 acc = make_float2(0.f, 0.f);
    int s_next = (beg < end) ? csr[beg] : 0;
    for (int i = beg; i < end; ++i) {
        const int s = s_next;
        if (i + 1 < end) s_next = csr[i + 1];
        const float2 asv = *(const float2*)(as_ + 2 * s);
        const float a = h ? asv.y : asv.x;
        float e = a + adh; e = e > 0.f ? e : 0.2f * e;
        const float alpha = __expf(e - mh) * rinv;
        const float2 v = *(const float2*)(S + (size_t)s * 128 + 2 * lane);
        acc.x = fmaf(alpha, v.x, acc.x);
        acc.y = fmaf(alpha, v.y, acc.y);
    }
    if (mode == 2) {
        float ox = acc.x + __shfl_xor(acc.x, 32);
        float oy = acc.y + __shfl_xor(acc.y, 32);
        if (lane < 32) {
            ox = 0.5f * ox + bias[2 * lane];
            oy = 0.5f * oy + bias[2 * lane + 1];
            *(float2*)(out + (size_t)d * 64 + 2 * lane) =
                make_float2(fmaxf(ox, 0.f), fmaxf(oy, 0.f));
        }
    } else {
        float ox = acc.x + bias[2 * lane];
        float oy = acc.y + bias[2 * lane + 1];
        if (mode == 0) { ox = ox > 0.f ? ox : expm1f(ox); oy = oy > 0.f ? oy : expm1f(oy); }
        else           { ox = fmaxf(ox, 0.f);             oy = fmaxf(oy, 0.f); }
        *(float2*)(out + (size_t)d * 128 + 2 * lane) = make_float2(ox, oy);
    }
}

extern "C" void kernel_launch(void* const* d_in, const int* in_sizes, int n_in,
                              void* d_out, int out_size, void* d_ws, size_t ws_size,
                              hipStream_t stream) {
    const float* X   = (const float*)d_in[0];
    const void*  EI  = d_in[1];
    const float* W0  = (const float*)d_in[2];
    const float* as0 = (const float*)d_in[3];
    const float* ad0 = (const float*)d_in[4];
    const float* b0  = (const float*)d_in[5];
    const float* W1  = (const float*)d_in[6];
    const float* as1 = (const float*)d_in[7];
    const float* ad1 = (const float*)d_in[8];
    const float* b1  = (const float*)d_in[9];
    const float* W2  = (const float*)d_in[10];
    const float* as2 = (const float*)d_in[11];
    const float* ad2 = (const float*)d_in[12];
    const float* b2  = (const float*)d_in[13];

    const int N  = in_sizes[0] / 128;   // 50000
    const int E  = in_sizes[1] / 2;     // 1600000
    const int ET = E + N;               // + self loops
    const int NB = (N + SCAN_BLOCK - 1) / SCAN_BLOCK;  // scan blocks (196)

    char* p = (char*)d_ws;
    size_t used = 0;
    auto alloc = [&](size_t bytes) -> void* {
        void* r = p + used;
        used += (bytes + 255) & ~(size_t)255;
        return r;
    };
    float* S    = (float*)alloc((size_t)N * 128 * 4);
    float* H0   = (float*)alloc((size_t)N * 128 * 4);
    float* H1   = (float*)alloc((size_t)N * 128 * 4);
    int*   csr  = (int*)alloc((size_t)ET * 4);
    int*   rowp = (int*)alloc((size_t)(N + 1) * 4);
    int*   cur  = (int*)alloc((size_t)N * 4);
    int*   cnt  = (int*)alloc((size_t)N * 4);
    int*   part = (int*)alloc((size_t)N * 4);
    int*   bsum = (int*)alloc((size_t)NB * 4);
    float* asb  = (float*)alloc((size_t)N * 2 * 4);
    float* adb  = (float*)alloc((size_t)N * 2 * 4);
    int*   flag = (int*)alloc(256);
    if (used > ws_size) return;  // fail loudly (validation will catch)

    hipMemsetAsync(cnt, 0, (size_t)N * 4, stream);
    detect_i64<<<1, 64, 0, stream>>>((const unsigned*)EI, flag);
    gat_count<<<2048, 256, 0, stream>>>(EI, flag, E, N, cnt);
    scan_stage1<<<NB, SCAN_BLOCK, 0, stream>>>(cnt, part, bsum, N);
    scan_stage2<<<1, 64, 0, stream>>>(bsum, NB, rowp, N);
    scan_stage3<<<NB, SCAN_BLOCK, 0, stream>>>(part, cnt, bsum, rowp, cur, N);
    gat_scatter<<<2048, 256, 0, stream>>>(EI, flag, E, N, cur, csr);

    const int gemm_blocks = (((N + 1) / 2) + 3) / 4;
    const int agg_blocks  = (N + 3) / 4;

    // layer 0: GATConv(128 -> 64, H=2, concat) + ELU
    gemm_alpha<<<gemm_blocks, 256, 0, stream>>>(X, W0, as0, ad0, S, asb, adb, N);
    gat_aggregate<<<agg_blocks, 256, 0, stream>>>(S, asb, adb, rowp, csr, b0, H0, N, 0);
    // layer 1: GATConv(128 -> 64, H=2, concat) + ReLU
    gemm_alpha<<<gemm_blocks, 256, 0, stream>>>(H0, W1, as1, ad1, S, asb, adb, N);
    gat_aggregate<<<agg_blocks, 256, 0, stream>>>(S, asb, adb, rowp, csr, b1, H1, N, 1);
    // layer 2: GATConvMean(128 -> 64, H=2, mean) + ReLU
    gemm_alpha<<<gemm_blocks, 256, 0, stream>>>(H1, W2, as2, ad2, S, asb, adb, N);
    gat_aggregate<<<agg_blocks, 256, 0, stream>>>(S, asb, adb, rowp, csr, b2, (float*)d_out, N, 2);
}

// Round 3
// 744.073 us; speedup vs baseline: 2.5903x; 2.0811x over previous
//
#include <hip/hip_runtime.h>
#include <hip/hip_bf16.h>

// ---------------------------------------------------------------------------
// GAT link-prediction forward: 3 GATConv layers on a fixed graph.
// R1: hierarchical scan (385us serial tail -> ~10us).
// R2: register-tiled f32 GEMM (shfl-broadcast inner loop was LDS-pipe bound:
//     VALUBusy 8.7%, 318us/dispatch; now 8x4 acc/thread, X-tile in LDS,
//     W via L1/L2).
// ---------------------------------------------------------------------------

#define SCAN_BLOCK 256

// Detect whether edge_index arrived as int64 (high words all zero) or int32.
__global__ void detect_i64(const unsigned* __restrict__ ei, int* __restrict__ flag) {
    if (threadIdx.x == 0 && blockIdx.x == 0) {
        int allz = 1;
        for (int i = 0; i < 128; ++i)
            if (ei[2 * i + 1] != 0u) { allz = 0; break; }
        *flag = allz;
    }
}

__global__ void gat_count(const void* __restrict__ ei, const int* __restrict__ flag,
                          int nE, int nN, int* __restrict__ cnt) {
    const int i64 = *flag;
    const long long total = (long long)nE + nN;
    const long long stride = (long long)gridDim.x * blockDim.x;
    for (long long i = (long long)blockIdx.x * blockDim.x + threadIdx.x; i < total; i += stride) {
        int d;
        if (i < nE) d = i64 ? (int)((const long long*)ei)[nE + i] : ((const int*)ei)[nE + i];
        else        d = (int)(i - nE);
        atomicAdd(&cnt[d], 1);
    }
}

// Stage 1: per-block (256-element) inclusive scan + block totals.
__global__ __launch_bounds__(SCAN_BLOCK) void scan_stage1(
    const int* __restrict__ cnt, int* __restrict__ partial, int* __restrict__ bsum, int n) {
    __shared__ int tmp[SCAN_BLOCK];
    const int i = blockIdx.x * SCAN_BLOCK + threadIdx.x;
    const int v = (i < n) ? cnt[i] : 0;
    tmp[threadIdx.x] = v;
    __syncthreads();
    #pragma unroll
    for (int off = 1; off < SCAN_BLOCK; off <<= 1) {
        const int t = (threadIdx.x >= off) ? tmp[threadIdx.x - off] : 0;
        __syncthreads();
        tmp[threadIdx.x] += t;
        __syncthreads();
    }
    if (i < n) partial[i] = tmp[threadIdx.x];
    if (threadIdx.x == SCAN_BLOCK - 1) bsum[blockIdx.x] = tmp[threadIdx.x];
}

// Stage 2: one wave exclusive-scans the block sums in place; writes rowp[n].
__global__ void scan_stage2(int* __restrict__ bsum, int nb, int* __restrict__ rowp, int n) {
    const int lane = threadIdx.x;  // blockDim = 64, grid = 1
    int carry = 0;
    for (int base = 0; base < nb; base += 64) {
        const int i = base + lane;
        const int v = (i < nb) ? bsum[i] : 0;
        int incl = v;
        #pragma unroll
        for (int off = 1; off < 64; off <<= 1) {
            const int t = __shfl_up(incl, off);
            if (lane >= off) incl += t;
        }
        if (i < nb) bsum[i] = carry + incl - v;  // exclusive
        carry += __shfl(incl, 63);
    }
    if (lane == 0) rowp[n] = carry;
}

// Stage 3: rowp[i] = bsumEx[block] + (inclusive - v)  (exclusive global scan).
__global__ __launch_bounds__(SCAN_BLOCK) void scan_stage3(
    const int* __restrict__ partial, const int* __restrict__ cnt, const int* __restrict__ bsum,
    int* __restrict__ rowp, int* __restrict__ cur, int n) {
    const int i = blockIdx.x * SCAN_BLOCK + threadIdx.x;
    if (i < n) {
        const int e = bsum[i >> 8] + partial[i] - cnt[i];
        rowp[i] = e;
        cur[i] = e;
    }
}

__global__ void gat_scatter(const void* __restrict__ ei, const int* __restrict__ flag,
                            int nE, int nN, int* __restrict__ cur, int* __restrict__ csr) {
    const int i64 = *flag;
    const long long total = (long long)nE + nN;
    const long long stride = (long long)gridDim.x * blockDim.x;
    for (long long i = (long long)blockIdx.x * blockDim.x + threadIdx.x; i < total; i += stride) {
        int s, d;
        if (i < nE) {
            if (i64) { s = (int)((const long long*)ei)[i]; d = (int)((const long long*)ei)[nE + i]; }
            else     { s = ((const int*)ei)[i];            d = ((const int*)ei)[nE + i]; }
        } else { s = d = (int)(i - nE); }
        const int pos = atomicAdd(&cur[d], 1);
        csr[pos] = s;
    }
}

// S = Xin @ W (50000x128 @ 128x128 f32), register-tiled.
// Block: 64-row tile, 256 threads. Thread (rowg=tid>>5, col4=tid&31) computes
// rows rowg*8..+7 x cols col4*4..+3 (8x4 = 32 acc). X-tile in LDS (32KB);
// W via L1/L2 (shared across all blocks, coalesced float4 reads).
// Epilogue: alpha_src/alpha_dst per head via 16-lane shfl_xor reduction.
__global__ __launch_bounds__(256) void gemm_alpha(
    const float* __restrict__ Xin, const float* __restrict__ W,
    const float* __restrict__ avs, const float* __restrict__ avd,
    float* __restrict__ S, float* __restrict__ as_, float* __restrict__ ad_, int n) {
    __shared__ float Xl[64][128];
    const int tid = threadIdx.x;
    const int row0 = blockIdx.x * 64;
    for (int i = tid; i < 64 * 32; i += 256) {
        const int r = i >> 5, c4 = i & 31;
        const int gr = row0 + r;
        float4 v = (gr < n) ? ((const float4*)(Xin + (size_t)gr * 128))[c4]
                            : make_float4(0.f, 0.f, 0.f, 0.f);
        ((float4*)(&Xl[r][0]))[c4] = v;
    }
    __syncthreads();
    const int col4 = tid & 31;   // cols 4*col4 .. +3 (head = col4>>4)
    const int rowg = tid >> 5;   // rows 8*rowg .. +7
    float4 acc[8];
    #pragma unroll
    for (int r = 0; r < 8; ++r) acc[r] = make_float4(0.f, 0.f, 0.f, 0.f);
    const float* Wc = W + col4 * 4;
    for (int kk = 0; kk < 128; kk += 4) {
        const float4 w0 = *(const float4*)(Wc + (size_t)(kk + 0) * 128);
        const float4 w1 = *(const float4*)(Wc + (size_t)(kk + 1) * 128);
        const float4 w2 = *(const float4*)(Wc + (size_t)(kk + 2) * 128);
        const float4 w3 = *(const float4*)(Wc + (size_t)(kk + 3) * 128);
        #pragma unroll
        for (int r = 0; r < 8; ++r) {
            const float4 x = *(const float4*)(&Xl[rowg * 8 + r][kk]);
            acc[r].x = fmaf(x.x, w0.x, acc[r].x); acc[r].y = fmaf(x.x, w0.y, acc[r].y);
            acc[r].z = fmaf(x.x, w0.z, acc[r].z); acc[r].w = fmaf(x.x, w0.w, acc[r].w);
            acc[r].x = fmaf(x.y, w1.x, acc[r].x); acc[r].y = fmaf(x.y, w1.y, acc[r].y);
            acc[r].z = fmaf(x.y, w1.z, acc[r].z); acc[r].w = fmaf(x.y, w1.w, acc[r].w);
            acc[r].x = fmaf(x.z, w2.x, acc[r].x); acc[r].y = fmaf(x.z, w2.y, acc[r].y);
            acc[r].z = fmaf(x.z, w2.z, acc[r].z); acc[r].w = fmaf(x.z, w2.w, acc[r].w);
            acc[r].x = fmaf(x.w, w3.x, acc[r].x); acc[r].y = fmaf(x.w, w3.y, acc[r].y);
            acc[r].z = fmaf(x.w, w3.z, acc[r].z); acc[r].w = fmaf(x.w, w3.w, acc[r].w);
        }
    }
    const float4 av = ((const float4*)avs)[col4];
    const float4 dv = ((const float4*)avd)[col4];
    #pragma unroll
    for (int r = 0; r < 8; ++r) {
        const int grow = row0 + rowg * 8 + r;
        if (grow < n) ((float4*)(S + (size_t)grow * 128))[col4] = acc[r];
        float ps = acc[r].x * av.x + acc[r].y * av.y + acc[r].z * av.z + acc[r].w * av.w;
        float pd = acc[r].x * dv.x + acc[r].y * dv.y + acc[r].z * dv.z + acc[r].w * dv.w;
        #pragma unroll
        for (int off = 8; off; off >>= 1) {  // reduce 16 col-lanes of this head
            ps += __shfl_xor(ps, off);
            pd += __shfl_xor(pd, off);
        }
        if ((col4 & 15) == 0 && grow < n) {
            const int h = col4 >> 4;
            as_[2 * grow + h] = ps;
            ad_[2 * grow + h] = pd;
        }
    }
}

// One wave per destination node: exact segment softmax (2 scalar passes over
// in-edges) + attention-weighted gather of s rows. mode 0=ELU(concat),
// 1=ReLU(concat), 2=ReLU(head-mean).
__global__ __launch_bounds__(256) void gat_aggregate(
    const float* __restrict__ S, const float* __restrict__ as_, const float* __restrict__ ad_,
    const int* __restrict__ rowp, const int* __restrict__ csr,
    const float* __restrict__ bias, float* __restrict__ out, int n, int mode) {
    const int lane = threadIdx.x & 63;
    const int d = (blockIdx.x * blockDim.x + threadIdx.x) >> 6;
    if (d >= n) return;
    const int beg = rowp[d], end = rowp[d + 1];
    const int h = lane >> 5;
    const float2 adv = *(const float2*)(ad_ + 2 * d);
    // pass 1: per-head max of e = leakyrelu(as[src] + ad[dst])
    float m0 = -1e30f, m1 = -1e30f;
    for (int i = beg + lane; i < end; i += 64) {
        const int s = csr[i];
        const float2 asv = *(const float2*)(as_ + 2 * s);
        float e0 = asv.x + adv.x; e0 = e0 > 0.f ? e0 : 0.2f * e0;
        float e1 = asv.y + adv.y; e1 = e1 > 0.f ? e1 : 0.2f * e1;
        m0 = fmaxf(m0, e0); m1 = fmaxf(m1, e1);
    }
    #pragma unroll
    for (int off = 32; off; off >>= 1) {
        m0 = fmaxf(m0, __shfl_xor(m0, off));
        m1 = fmaxf(m1, __shfl_xor(m1, off));
    }
    // pass 2: per-head denom
    float s0 = 0.f, s1 = 0.f;
    for (int i = beg + lane; i < end; i += 64) {
        const int s = csr[i];
        const float2 asv = *(const float2*)(as_ + 2 * s);
        float e0 = asv.x + adv.x; e0 = e0 > 0.f ? e0 : 0.2f * e0;
        float e1 = asv.y + adv.y; e1 = e1 > 0.f ? e1 : 0.2f * e1;
        s0 += __expf(e0 - m0); s1 += __expf(e1 - m1);
    }
    #pragma unroll
    for (int off = 32; off; off >>= 1) {
        s0 += __shfl_xor(s0, off);
        s1 += __shfl_xor(s1, off);
    }
    const float mh   = h ? m1 : m0;
    const float rinv = 1.f / (h ? s1 : s0);
    const float adh  = h ? adv.y : adv.x;
    // pass 3: gather + accumulate. lane l holds cols 2l,2l+1 (head = l>>5).
    float2 acc = make_float2(0.f, 0.f);
    int s_next = (beg < end) ? csr[beg] : 0;
    for (int i = beg; i < end; ++i) {
        const int s = s_next;
        if (i + 1 < end) s_next = csr[i + 1];
        const float2 asv = *(const float2*)(as_ + 2 * s);
        const float a = h ? asv.y : asv.x;
        float e = a + adh; e = e > 0.f ? e : 0.2f * e;
        const float alpha = __expf(e - mh) * rinv;
        const float2 v = *(const float2*)(S + (size_t)s * 128 + 2 * lane);
        acc.x = fmaf(alpha, v.x, acc.x);
        acc.y = fmaf(alpha, v.y, acc.y);
    }
    if (mode == 2) {
        float ox = acc.x + __shfl_xor(acc.x, 32);
        float oy = acc.y + __shfl_xor(acc.y, 32);
        if (lane < 32) {
            ox = 0.5f * ox + bias[2 * lane];
            oy = 0.5f * oy + bias[2 * lane + 1];
            *(float2*)(out + (size_t)d * 64 + 2 * lane) =
                make_float2(fmaxf(ox, 0.f), fmaxf(oy, 0.f));
        }
    } else {
        float ox = acc.x + bias[2 * lane];
        float oy = acc.y + bias[2 * lane + 1];
        if (mode == 0) { ox = ox > 0.f ? ox : expm1f(ox); oy = oy > 0.f ? oy : expm1f(oy); }
        else           { ox = fmaxf(ox, 0.f);             oy = fmaxf(oy, 0.f); }
        *(float2*)(out + (size_t)d * 128 + 2 * lane) = make_float2(ox, oy);
    }
}

extern "C" void kernel_launch(void* const* d_in, const int* in_sizes, int n_in,
                              void* d_out, int out_size, void* d_ws, size_t ws_size,
                              hipStream_t stream) {
    const float* X   = (const float*)d_in[0];
    const void*  EI  = d_in[1];
    const float* W0  = (const float*)d_in[2];
    const float* as0 = (const float*)d_in[3];
    const float* ad0 = (const float*)d_in[4];
    const float* b0  = (const float*)d_in[5];
    const float* W1  = (const float*)d_in[6];
    const float* as1 = (const float*)d_in[7];
    const float* ad1 = (const float*)d_in[8];
    const float* b1  = (const float*)d_in[9];
    const float* W2  = (const float*)d_in[10];
    const float* as2 = (const float*)d_in[11];
    const float* ad2 = (const float*)d_in[12];
    const float* b2  = (const float*)d_in[13];

    const int N  = in_sizes[0] / 128;   // 50000
    const int E  = in_sizes[1] / 2;     // 1600000
    const int ET = E + N;               // + self loops
    const int NB = (N + SCAN_BLOCK - 1) / SCAN_BLOCK;  // scan blocks (196)

    char* p = (char*)d_ws;
    size_t used = 0;
    auto alloc = [&](size_t bytes) -> void* {
        void* r = p + used;
        used += (bytes + 255) & ~(size_t)255;
        return r;
    };
    float* S    = (float*)alloc((size_t)N * 128 * 4);
    float* H0   = (float*)alloc((size_t)N * 128 * 4);
    float* H1   = (float*)alloc((size_t)N * 128 * 4);
    int*   csr  = (int*)alloc((size_t)ET * 4);
    int*   rowp = (int*)alloc((size_t)(N + 1) * 4);
    int*   cur  = (int*)alloc((size_t)N * 4);
    int*   cnt  = (int*)alloc((size_t)N * 4);
    int*   part = (int*)alloc((size_t)N * 4);
    int*   bsum = (int*)alloc((size_t)NB * 4);
    float* asb  = (float*)alloc((size_t)N * 2 * 4);
    float* adb  = (float*)alloc((size_t)N * 2 * 4);
    int*   flag = (int*)alloc(256);
    if (used > ws_size) return;  // fail loudly (validation will catch)

    hipMemsetAsync(cnt, 0, (size_t)N * 4, stream);
    detect_i64<<<1, 64, 0, stream>>>((const unsigned*)EI, flag);
    gat_count<<<2048, 256, 0, stream>>>(EI, flag, E, N, cnt);
    scan_stage1<<<NB, SCAN_BLOCK, 0, stream>>>(cnt, part, bsum, N);
    scan_stage2<<<1, 64, 0, stream>>>(bsum, NB, rowp, N);
    scan_stage3<<<NB, SCAN_BLOCK, 0, stream>>>(part, cnt, bsum, rowp, cur, N);
    gat_scatter<<<2048, 256, 0, stream>>>(EI, flag, E, N, cur, csr);

    const int gemm_blocks = (N + 63) / 64;
    const int agg_blocks  = (N + 3) / 4;

    // layer 0: GATConv(128 -> 64, H=2, concat) + ELU
    gemm_alpha<<<gemm_blocks, 256, 0, stream>>>(X, W0, as0, ad0, S, asb, adb, N);
    gat_aggregate<<<agg_blocks, 256, 0, stream>>>(S, asb, adb, rowp, csr, b0, H0, N, 0);
    // layer 1: GATConv(128 -> 64, H=2, concat) + ReLU
    gemm_alpha<<<gemm_blocks, 256, 0, stream>>>(H0, W1, as1, ad1, S, asb, adb, N);
    gat_aggregate<<<agg_blocks, 256, 0, stream>>>(S, asb, adb, rowp, csr, b1, H1, N, 1);
    // layer 2: GATConvMean(128 -> 64, H=2, mean) + ReLU
    gemm_alpha<<<gemm_blocks, 256, 0, stream>>>(H1, W2, as2, ad2, S, asb, adb, N);
    gat_aggregate<<<agg_blocks, 256, 0, stream>>>(S, asb, adb, rowp, csr, b2, (float*)d_out, N, 2);
}

// Round 4
// 709.914 us; speedup vs baseline: 2.7149x; 1.0481x over previous
//
#include <hip/hip_runtime.h>
#include <hip/hip_bf16.h>

// ---------------------------------------------------------------------------
// GAT link-prediction forward: 3 GATConv layers on a fixed graph.
// R1: hierarchical scan (385us serial tail -> ~10us).
// R2: register-tiled f32 GEMM (318us -> ~25us/dispatch).
// R3: aggregate split: gat_stats (alpha materialized once, registers for
//     deg<=64) + gat_gather (2 edges/iter, float4 lanes, no exp) — old
//     kernel was serial-per-edge with 3x redundant exp (VALU 53%).
// ---------------------------------------------------------------------------

#define SCAN_BLOCK 256

// Detect whether edge_index arrived as int64 (high words all zero) or int32.
__global__ void detect_i64(const unsigned* __restrict__ ei, int* __restrict__ flag) {
    if (threadIdx.x == 0 && blockIdx.x == 0) {
        int allz = 1;
        for (int i = 0; i < 128; ++i)
            if (ei[2 * i + 1] != 0u) { allz = 0; break; }
        *flag = allz;
    }
}

__global__ void gat_count(const void* __restrict__ ei, const int* __restrict__ flag,
                          int nE, int nN, int* __restrict__ cnt) {
    const int i64 = *flag;
    const long long total = (long long)nE + nN;
    const long long stride = (long long)gridDim.x * blockDim.x;
    for (long long i = (long long)blockIdx.x * blockDim.x + threadIdx.x; i < total; i += stride) {
        int d;
        if (i < nE) d = i64 ? (int)((const long long*)ei)[nE + i] : ((const int*)ei)[nE + i];
        else        d = (int)(i - nE);
        atomicAdd(&cnt[d], 1);
    }
}

// Stage 1: per-block (256-element) inclusive scan + block totals.
__global__ __launch_bounds__(SCAN_BLOCK) void scan_stage1(
    const int* __restrict__ cnt, int* __restrict__ partial, int* __restrict__ bsum, int n) {
    __shared__ int tmp[SCAN_BLOCK];
    const int i = blockIdx.x * SCAN_BLOCK + threadIdx.x;
    const int v = (i < n) ? cnt[i] : 0;
    tmp[threadIdx.x] = v;
    __syncthreads();
    #pragma unroll
    for (int off = 1; off < SCAN_BLOCK; off <<= 1) {
        const int t = (threadIdx.x >= off) ? tmp[threadIdx.x - off] : 0;
        __syncthreads();
        tmp[threadIdx.x] += t;
        __syncthreads();
    }
    if (i < n) partial[i] = tmp[threadIdx.x];
    if (threadIdx.x == SCAN_BLOCK - 1) bsum[blockIdx.x] = tmp[threadIdx.x];
}

// Stage 2: one wave exclusive-scans the block sums in place; writes rowp[n].
__global__ void scan_stage2(int* __restrict__ bsum, int nb, int* __restrict__ rowp, int n) {
    const int lane = threadIdx.x;  // blockDim = 64, grid = 1
    int carry = 0;
    for (int base = 0; base < nb; base += 64) {
        const int i = base + lane;
        const int v = (i < nb) ? bsum[i] : 0;
        int incl = v;
        #pragma unroll
        for (int off = 1; off < 64; off <<= 1) {
            const int t = __shfl_up(incl, off);
            if (lane >= off) incl += t;
        }
        if (i < nb) bsum[i] = carry + incl - v;  // exclusive
        carry += __shfl(incl, 63);
    }
    if (lane == 0) rowp[n] = carry;
}

// Stage 3: rowp[i] = bsumEx[block] + (inclusive - v)  (exclusive global scan).
__global__ __launch_bounds__(SCAN_BLOCK) void scan_stage3(
    const int* __restrict__ partial, const int* __restrict__ cnt, const int* __restrict__ bsum,
    int* __restrict__ rowp, int* __restrict__ cur, int n) {
    const int i = blockIdx.x * SCAN_BLOCK + threadIdx.x;
    if (i < n) {
        const int e = bsum[i >> 8] + partial[i] - cnt[i];
        rowp[i] = e;
        cur[i] = e;
    }
}

__global__ void gat_scatter(const void* __restrict__ ei, const int* __restrict__ flag,
                            int nE, int nN, int* __restrict__ cur, int* __restrict__ csr) {
    const int i64 = *flag;
    const long long total = (long long)nE + nN;
    const long long stride = (long long)gridDim.x * blockDim.x;
    for (long long i = (long long)blockIdx.x * blockDim.x + threadIdx.x; i < total; i += stride) {
        int s, d;
        if (i < nE) {
            if (i64) { s = (int)((const long long*)ei)[i]; d = (int)((const long long*)ei)[nE + i]; }
            else     { s = ((const int*)ei)[i];            d = ((const int*)ei)[nE + i]; }
        } else { s = d = (int)(i - nE); }
        const int pos = atomicAdd(&cur[d], 1);
        csr[pos] = s;
    }
}

// S = Xin @ W (50000x128 @ 128x128 f32), register-tiled.
__global__ __launch_bounds__(256) void gemm_alpha(
    const float* __restrict__ Xin, const float* __restrict__ W,
    const float* __restrict__ avs, const float* __restrict__ avd,
    float* __restrict__ S, float* __restrict__ as_, float* __restrict__ ad_, int n) {
    __shared__ float Xl[64][128];
    const int tid = threadIdx.x;
    const int row0 = blockIdx.x * 64;
    for (int i = tid; i < 64 * 32; i += 256) {
        const int r = i >> 5, c4 = i & 31;
        const int gr = row0 + r;
        float4 v = (gr < n) ? ((const float4*)(Xin + (size_t)gr * 128))[c4]
                            : make_float4(0.f, 0.f, 0.f, 0.f);
        ((float4*)(&Xl[r][0]))[c4] = v;
    }
    __syncthreads();
    const int col4 = tid & 31;   // cols 4*col4 .. +3 (head = col4>>4)
    const int rowg = tid >> 5;   // rows 8*rowg .. +7
    float4 acc[8];
    #pragma unroll
    for (int r = 0; r < 8; ++r) acc[r] = make_float4(0.f, 0.f, 0.f, 0.f);
    const float* Wc = W + col4 * 4;
    for (int kk = 0; kk < 128; kk += 4) {
        const float4 w0 = *(const float4*)(Wc + (size_t)(kk + 0) * 128);
        const float4 w1 = *(const float4*)(Wc + (size_t)(kk + 1) * 128);
        const float4 w2 = *(const float4*)(Wc + (size_t)(kk + 2) * 128);
        const float4 w3 = *(const float4*)(Wc + (size_t)(kk + 3) * 128);
        #pragma unroll
        for (int r = 0; r < 8; ++r) {
            const float4 x = *(const float4*)(&Xl[rowg * 8 + r][kk]);
            acc[r].x = fmaf(x.x, w0.x, acc[r].x); acc[r].y = fmaf(x.x, w0.y, acc[r].y);
            acc[r].z = fmaf(x.x, w0.z, acc[r].z); acc[r].w = fmaf(x.x, w0.w, acc[r].w);
            acc[r].x = fmaf(x.y, w1.x, acc[r].x); acc[r].y = fmaf(x.y, w1.y, acc[r].y);
            acc[r].z = fmaf(x.y, w1.z, acc[r].z); acc[r].w = fmaf(x.y, w1.w, acc[r].w);
            acc[r].x = fmaf(x.z, w2.x, acc[r].x); acc[r].y = fmaf(x.z, w2.y, acc[r].y);
            acc[r].z = fmaf(x.z, w2.z, acc[r].z); acc[r].w = fmaf(x.z, w2.w, acc[r].w);
            acc[r].x = fmaf(x.w, w3.x, acc[r].x); acc[r].y = fmaf(x.w, w3.y, acc[r].y);
            acc[r].z = fmaf(x.w, w3.z, acc[r].z); acc[r].w = fmaf(x.w, w3.w, acc[r].w);
        }
    }
    const float4 av = ((const float4*)avs)[col4];
    const float4 dv = ((const float4*)avd)[col4];
    #pragma unroll
    for (int r = 0; r < 8; ++r) {
        const int grow = row0 + rowg * 8 + r;
        if (grow < n) ((float4*)(S + (size_t)grow * 128))[col4] = acc[r];
        float ps = acc[r].x * av.x + acc[r].y * av.y + acc[r].z * av.z + acc[r].w * av.w;
        float pd = acc[r].x * dv.x + acc[r].y * dv.y + acc[r].z * dv.z + acc[r].w * dv.w;
        #pragma unroll
        for (int off = 8; off; off >>= 1) {  // reduce 16 col-lanes of this head
            ps += __shfl_xor(ps, off);
            pd += __shfl_xor(pd, off);
        }
        if ((col4 & 15) == 0 && grow < n) {
            const int h = col4 >> 4;
            as_[2 * grow + h] = ps;
            ad_[2 * grow + h] = pd;
        }
    }
}

// Per-dst softmax stats; materializes alpha[i] (float2 per csr slot).
// Fast path deg<=64: e kept in registers, single pass over memory.
__global__ __launch_bounds__(256) void gat_stats(
    const float* __restrict__ as_, const float* __restrict__ ad_,
    const int* __restrict__ rowp, const int* __restrict__ csr,
    float2* __restrict__ alpha, int n) {
    const int lane = threadIdx.x & 63;
    const int d = (blockIdx.x * blockDim.x + threadIdx.x) >> 6;
    if (d >= n) return;
    const int beg = rowp[d], end = rowp[d + 1];
    const float2 adv = *(const float2*)(ad_ + 2 * d);
    if (end - beg <= 64) {
        const int i = beg + lane;
        const bool has = i < end;
        float e0 = -1e30f, e1 = -1e30f;
        if (has) {
            const int s = csr[i];
            const float2 asv = *(const float2*)(as_ + 2 * s);
            e0 = asv.x + adv.x; e0 = e0 > 0.f ? e0 : 0.2f * e0;
            e1 = asv.y + adv.y; e1 = e1 > 0.f ? e1 : 0.2f * e1;
        }
        float m0 = e0, m1 = e1;
        #pragma unroll
        for (int off = 32; off; off >>= 1) {
            m0 = fmaxf(m0, __shfl_xor(m0, off));
            m1 = fmaxf(m1, __shfl_xor(m1, off));
        }
        float p0 = has ? __expf(e0 - m0) : 0.f;
        float p1 = has ? __expf(e1 - m1) : 0.f;
        float s0 = p0, s1 = p1;
        #pragma unroll
        for (int off = 32; off; off >>= 1) {
            s0 += __shfl_xor(s0, off);
            s1 += __shfl_xor(s1, off);
        }
        if (has) alpha[i] = make_float2(p0 / s0, p1 / s1);
    } else {
        float m0 = -1e30f, m1 = -1e30f;
        for (int i = beg + lane; i < end; i += 64) {
            const int s = csr[i];
            const float2 asv = *(const float2*)(as_ + 2 * s);
            float e0 = asv.x + adv.x; e0 = e0 > 0.f ? e0 : 0.2f * e0;
            float e1 = asv.y + adv.y; e1 = e1 > 0.f ? e1 : 0.2f * e1;
            m0 = fmaxf(m0, e0); m1 = fmaxf(m1, e1);
        }
        #pragma unroll
        for (int off = 32; off; off >>= 1) {
            m0 = fmaxf(m0, __shfl_xor(m0, off));
            m1 = fmaxf(m1, __shfl_xor(m1, off));
        }
        float s0 = 0.f, s1 = 0.f;
        for (int i = beg + lane; i < end; i += 64) {
            const int s = csr[i];
            const float2 asv = *(const float2*)(as_ + 2 * s);
            float e0 = asv.x + adv.x; e0 = e0 > 0.f ? e0 : 0.2f * e0;
            float e1 = asv.y + adv.y; e1 = e1 > 0.f ? e1 : 0.2f * e1;
            s0 += __expf(e0 - m0); s1 += __expf(e1 - m1);
        }
        #pragma unroll
        for (int off = 32; off; off >>= 1) {
            s0 += __shfl_xor(s0, off);
            s1 += __shfl_xor(s1, off);
        }
        const float r0 = 1.f / s0, r1 = 1.f / s1;
        for (int i = beg + lane; i < end; i += 64) {
            const int s = csr[i];
            const float2 asv = *(const float2*)(as_ + 2 * s);
            float e0 = asv.x + adv.x; e0 = e0 > 0.f ? e0 : 0.2f * e0;
            float e1 = asv.y + adv.y; e1 = e1 > 0.f ? e1 : 0.2f * e1;
            alpha[i] = make_float2(__expf(e0 - m0) * r0, __expf(e1 - m1) * r1);
        }
    }
}

// Weighted gather: one wave per dst, 2 edges per iteration (half-wave each,
// float4 per lane -> 2x512B rows per wave-instruction). No exp, no softmax.
// mode 0=ELU(concat), 1=ReLU(concat), 2=ReLU(head-mean).
__global__ __launch_bounds__(256) void gat_gather(
    const float* __restrict__ S, const float2* __restrict__ alpha,
    const int* __restrict__ rowp, const int* __restrict__ csr,
    const float* __restrict__ bias, float* __restrict__ out, int n, int mode) {
    const int lane = threadIdx.x & 63;
    const int d = (blockIdx.x * blockDim.x + threadIdx.x) >> 6;
    if (d >= n) return;
    const int beg = rowp[d], end = rowp[d + 1];
    const int half = lane >> 5;   // which edge of the pair
    const int c4 = lane & 31;     // float4 col group (head = c4>>4)
    const int head = c4 >> 4;
    float4 acc = make_float4(0.f, 0.f, 0.f, 0.f);
    for (int i = beg; i < end; i += 2) {
        const int j = i + half;
        const bool valid = j < end;
        const int jj = valid ? j : i;
        const int s = csr[jj];
        const float2 a2 = alpha[jj];
        float a = head ? a2.y : a2.x;
        if (!valid) a = 0.f;
        const float4 v = ((const float4*)(S + ((size_t)s << 7)))[c4];
        acc.x = fmaf(a, v.x, acc.x);
        acc.y = fmaf(a, v.y, acc.y);
        acc.z = fmaf(a, v.z, acc.z);
        acc.w = fmaf(a, v.w, acc.w);
    }
    // combine even/odd edge halves (lane l and l+32 hold same col group)
    acc.x += __shfl_xor(acc.x, 32);
    acc.y += __shfl_xor(acc.y, 32);
    acc.z += __shfl_xor(acc.z, 32);
    acc.w += __shfl_xor(acc.w, 32);
    if (mode == 2) {
        // head-mean: lane c4<16 (head0 cols) pairs with c4+16 (head1 cols)
        float4 oth;
        oth.x = __shfl_xor(acc.x, 16);
        oth.y = __shfl_xor(acc.y, 16);
        oth.z = __shfl_xor(acc.z, 16);
        oth.w = __shfl_xor(acc.w, 16);
        if (lane < 16) {
            const float4 b = ((const float4*)bias)[c4];
            float4 o;
            o.x = fmaxf(0.5f * (acc.x + oth.x) + b.x, 0.f);
            o.y = fmaxf(0.5f * (acc.y + oth.y) + b.y, 0.f);
            o.z = fmaxf(0.5f * (acc.z + oth.z) + b.z, 0.f);
            o.w = fmaxf(0.5f * (acc.w + oth.w) + b.w, 0.f);
            ((float4*)(out + (size_t)d * 64))[c4] = o;
        }
    } else if (lane < 32) {
        const float4 b = ((const float4*)bias)[c4];
        float4 o;
        o.x = acc.x + b.x; o.y = acc.y + b.y; o.z = acc.z + b.z; o.w = acc.w + b.w;
        if (mode == 0) {
            o.x = o.x > 0.f ? o.x : expm1f(o.x);
            o.y = o.y > 0.f ? o.y : expm1f(o.y);
            o.z = o.z > 0.f ? o.z : expm1f(o.z);
            o.w = o.w > 0.f ? o.w : expm1f(o.w);
        } else {
            o.x = fmaxf(o.x, 0.f); o.y = fmaxf(o.y, 0.f);
            o.z = fmaxf(o.z, 0.f); o.w = fmaxf(o.w, 0.f);
        }
        ((float4*)(out + (size_t)d * 128))[c4] = o;
    }
}

extern "C" void kernel_launch(void* const* d_in, const int* in_sizes, int n_in,
                              void* d_out, int out_size, void* d_ws, size_t ws_size,
                              hipStream_t stream) {
    const float* X   = (const float*)d_in[0];
    const void*  EI  = d_in[1];
    const float* W0  = (const float*)d_in[2];
    const float* as0 = (const float*)d_in[3];
    const float* ad0 = (const float*)d_in[4];
    const float* b0  = (const float*)d_in[5];
    const float* W1  = (const float*)d_in[6];
    const float* as1 = (const float*)d_in[7];
    const float* ad1 = (const float*)d_in[8];
    const float* b1  = (const float*)d_in[9];
    const float* W2  = (const float*)d_in[10];
    const float* as2 = (const float*)d_in[11];
    const float* ad2 = (const float*)d_in[12];
    const float* b2  = (const float*)d_in[13];

    const int N  = in_sizes[0] / 128;   // 50000
    const int E  = in_sizes[1] / 2;     // 1600000
    const int ET = E + N;               // + self loops
    const int NB = (N + SCAN_BLOCK - 1) / SCAN_BLOCK;  // scan blocks (196)

    char* p = (char*)d_ws;
    size_t used = 0;
    auto alloc = [&](size_t bytes) -> void* {
        void* r = p + used;
        used += (bytes + 255) & ~(size_t)255;
        return r;
    };
    float*  S    = (float*)alloc((size_t)N * 128 * 4);
    float*  H0   = (float*)alloc((size_t)N * 128 * 4);
    float*  H1   = (float*)alloc((size_t)N * 128 * 4);
    int*    csr  = (int*)alloc((size_t)ET * 4);
    float2* alp  = (float2*)alloc((size_t)ET * 8);
    int*    rowp = (int*)alloc((size_t)(N + 1) * 4);
    int*    cur  = (int*)alloc((size_t)N * 4);
    int*    cnt  = (int*)alloc((size_t)N * 4);
    int*    part = (int*)alloc((size_t)N * 4);
    int*    bsum = (int*)alloc((size_t)NB * 4);
    float*  asb  = (float*)alloc((size_t)N * 2 * 4);
    float*  adb  = (float*)alloc((size_t)N * 2 * 4);
    int*    flag = (int*)alloc(256);
    if (used > ws_size) return;  // fail loudly (validation will catch)

    hipMemsetAsync(cnt, 0, (size_t)N * 4, stream);
    detect_i64<<<1, 64, 0, stream>>>((const unsigned*)EI, flag);
    gat_count<<<2048, 256, 0, stream>>>(EI, flag, E, N, cnt);
    scan_stage1<<<NB, SCAN_BLOCK, 0, stream>>>(cnt, part, bsum, N);
    scan_stage2<<<1, 64, 0, stream>>>(bsum, NB, rowp, N);
    scan_stage3<<<NB, SCAN_BLOCK, 0, stream>>>(part, cnt, bsum, rowp, cur, N);
    gat_scatter<<<2048, 256, 0, stream>>>(EI, flag, E, N, cur, csr);

    const int gemm_blocks = (N + 63) / 64;
    const int wave_blocks = (N + 3) / 4;  // 4 waves/block, 1 dst/wave

    // layer 0: GATConv(128 -> 64, H=2, concat) + ELU
    gemm_alpha<<<gemm_blocks, 256, 0, stream>>>(X, W0, as0, ad0, S, asb, adb, N);
    gat_stats<<<wave_blocks, 256, 0, stream>>>(asb, adb, rowp, csr, alp, N);
    gat_gather<<<wave_blocks, 256, 0, stream>>>(S, alp, rowp, csr, b0, H0, N, 0);
    // layer 1: GATConv(128 -> 64, H=2, concat) + ReLU
    gemm_alpha<<<gemm_blocks, 256, 0, stream>>>(H0, W1, as1, ad1, S, asb, adb, N);
    gat_stats<<<wave_blocks, 256, 0, stream>>>(asb, adb, rowp, csr, alp, N);
    gat_gather<<<wave_blocks, 256, 0, stream>>>(S, alp, rowp, csr, b1, H1, N, 1);
    // layer 2: GATConvMean(128 -> 64, H=2, mean) + ReLU
    gemm_alpha<<<gemm_blocks, 256, 0, stream>>>(H1, W2, as2, ad2, S, asb, adb, N);
    gat_stats<<<wave_blocks, 256, 0, stream>>>(asb, adb, rowp, csr, alp, N);
    gat_gather<<<wave_blocks, 256, 0, stream>>>(S, alp, rowp, csr, b2, (float*)d_out, N, 2);
}

// Round 5
// 583.898 us; speedup vs baseline: 3.3008x; 1.2158x over previous
//
#include <hip/hip_runtime.h>
#include <hip/hip_bf16.h>

// ---------------------------------------------------------------------------
// GAT link-prediction forward: 3 GATConv layers on a fixed graph.
// R1: hierarchical scan (385us serial tail -> ~10us).
// R2: register-tiled f32 GEMM (318us -> ~25us/dispatch).
// R3: aggregate split into gat_stats + gat_gather.
// R4: CSR build reworked: single atomic pass (rank = atomicAdd returning old)
//     + atomic-free placement; both passes partitioned by contiguous dst
//     class (d/6250 == blockIdx&7 ~ XCD) so cnt lines and csr regions are
//     XCD-local (old scatter: WRITE_SIZE 103MB for 6.6MB csr = line
//     ping-pong). Gather: 2x unroll for MLP.
// ---------------------------------------------------------------------------

#define SCAN_BLOCK 256

// Detect whether edge_index arrived as int64 (high words all zero) or int32.
__global__ void detect_i64(const unsigned* __restrict__ ei, int* __restrict__ flag) {
    if (threadIdx.x == 0 && blockIdx.x == 0) {
        int allz = 1;
        for (int i = 0; i < 128; ++i)
            if (ei[2 * i + 1] != 0u) { allz = 0; break; }
        *flag = allz;
    }
}

// Pass 1: per-edge rank within its dst (atomicAdd returns old count).
// Blocks of class c = blockIdx&7 handle only dsts in [c*cw, (c+1)*cw) so the
// atomic cnt lines are XCD-local. rank[] written coalesced.
__global__ __launch_bounds__(256) void gat_rank(
    const void* __restrict__ ei, const int* __restrict__ flag, int nE, int nN,
    int* __restrict__ cnt, int* __restrict__ rank) {
    const int i64 = *flag;
    const int cw = (nN + 7) >> 3;
    const int lo = (blockIdx.x & 7) * cw;
    const long long total = (long long)nE + nN;
    const long long stride = (long long)(gridDim.x >> 3) * blockDim.x;
    for (long long i = (long long)(blockIdx.x >> 3) * blockDim.x + threadIdx.x;
         i < total; i += stride) {
        int d;
        if (i < nE) d = i64 ? (int)((const long long*)ei)[nE + i] : ((const int*)ei)[nE + i];
        else        d = (int)(i - nE);
        if ((unsigned)(d - lo) >= (unsigned)cw) continue;
        rank[i] = atomicAdd(&cnt[d], 1);
    }
}

// Stage 1: per-block (256-element) inclusive scan + block totals.
__global__ __launch_bounds__(SCAN_BLOCK) void scan_stage1(
    const int* __restrict__ cnt, int* __restrict__ partial, int* __restrict__ bsum, int n) {
    __shared__ int tmp[SCAN_BLOCK];
    const int i = blockIdx.x * SCAN_BLOCK + threadIdx.x;
    const int v = (i < n) ? cnt[i] : 0;
    tmp[threadIdx.x] = v;
    __syncthreads();
    #pragma unroll
    for (int off = 1; off < SCAN_BLOCK; off <<= 1) {
        const int t = (threadIdx.x >= off) ? tmp[threadIdx.x - off] : 0;
        __syncthreads();
        tmp[threadIdx.x] += t;
        __syncthreads();
    }
    if (i < n) partial[i] = tmp[threadIdx.x];
    if (threadIdx.x == SCAN_BLOCK - 1) bsum[blockIdx.x] = tmp[threadIdx.x];
}

// Stage 2: one wave exclusive-scans the block sums in place; writes rowp[n].
__global__ void scan_stage2(int* __restrict__ bsum, int nb, int* __restrict__ rowp, int n) {
    const int lane = threadIdx.x;  // blockDim = 64, grid = 1
    int carry = 0;
    for (int base = 0; base < nb; base += 64) {
        const int i = base + lane;
        const int v = (i < nb) ? bsum[i] : 0;
        int incl = v;
        #pragma unroll
        for (int off = 1; off < 64; off <<= 1) {
            const int t = __shfl_up(incl, off);
            if (lane >= off) incl += t;
        }
        if (i < nb) bsum[i] = carry + incl - v;  // exclusive
        carry += __shfl(incl, 63);
    }
    if (lane == 0) rowp[n] = carry;
}

// Stage 3: rowp[i] = bsumEx[block] + (inclusive - v)  (exclusive global scan).
__global__ __launch_bounds__(SCAN_BLOCK) void scan_stage3(
    const int* __restrict__ partial, const int* __restrict__ cnt, const int* __restrict__ bsum,
    int* __restrict__ rowp, int n) {
    const int i = blockIdx.x * SCAN_BLOCK + threadIdx.x;
    if (i < n) rowp[i] = bsum[i >> 8] + partial[i] - cnt[i];
}

// Pass 2: atomic-free placement. Same dst-class partition as gat_rank, so
// each class writes a contiguous ~E/8 csr region (XCD-local lines).
__global__ __launch_bounds__(256) void gat_place(
    const void* __restrict__ ei, const int* __restrict__ flag, int nE, int nN,
    const int* __restrict__ rowp, const int* __restrict__ rank, int* __restrict__ csr) {
    const int i64 = *flag;
    const int cw = (nN + 7) >> 3;
    const int lo = (blockIdx.x & 7) * cw;
    const long long total = (long long)nE + nN;
    const long long stride = (long long)(gridDim.x >> 3) * blockDim.x;
    for (long long i = (long long)(blockIdx.x >> 3) * blockDim.x + threadIdx.x;
         i < total; i += stride) {
        int s, d;
        if (i < nE) {
            d = i64 ? (int)((const long long*)ei)[nE + i] : ((const int*)ei)[nE + i];
            if ((unsigned)(d - lo) >= (unsigned)cw) continue;
            s = i64 ? (int)((const long long*)ei)[i] : ((const int*)ei)[i];
        } else {
            s = d = (int)(i - nE);
            if ((unsigned)(d - lo) >= (unsigned)cw) continue;
        }
        csr[rowp[d] + rank[i]] = s;
    }
}

// S = Xin @ W (50000x128 @ 128x128 f32), register-tiled.
__global__ __launch_bounds__(256) void gemm_alpha(
    const float* __restrict__ Xin, const float* __restrict__ W,
    const float* __restrict__ avs, const float* __restrict__ avd,
    float* __restrict__ S, float* __restrict__ as_, float* __restrict__ ad_, int n) {
    __shared__ float Xl[64][128];
    const int tid = threadIdx.x;
    const int row0 = blockIdx.x * 64;
    for (int i = tid; i < 64 * 32; i += 256) {
        const int r = i >> 5, c4 = i & 31;
        const int gr = row0 + r;
        float4 v = (gr < n) ? ((const float4*)(Xin + (size_t)gr * 128))[c4]
                            : make_float4(0.f, 0.f, 0.f, 0.f);
        ((float4*)(&Xl[r][0]))[c4] = v;
    }
    __syncthreads();
    const int col4 = tid & 31;   // cols 4*col4 .. +3 (head = col4>>4)
    const int rowg = tid >> 5;   // rows 8*rowg .. +7
    float4 acc[8];
    #pragma unroll
    for (int r = 0; r < 8; ++r) acc[r] = make_float4(0.f, 0.f, 0.f, 0.f);
    const float* Wc = W + col4 * 4;
    for (int kk = 0; kk < 128; kk += 4) {
        const float4 w0 = *(const float4*)(Wc + (size_t)(kk + 0) * 128);
        const float4 w1 = *(const float4*)(Wc + (size_t)(kk + 1) * 128);
        const float4 w2 = *(const float4*)(Wc + (size_t)(kk + 2) * 128);
        const float4 w3 = *(const float4*)(Wc + (size_t)(kk + 3) * 128);
        #pragma unroll
        for (int r = 0; r < 8; ++r) {
            const float4 x = *(const float4*)(&Xl[rowg * 8 + r][kk]);
            acc[r].x = fmaf(x.x, w0.x, acc[r].x); acc[r].y = fmaf(x.x, w0.y, acc[r].y);
            acc[r].z = fmaf(x.x, w0.z, acc[r].z); acc[r].w = fmaf(x.x, w0.w, acc[r].w);
            acc[r].x = fmaf(x.y, w1.x, acc[r].x); acc[r].y = fmaf(x.y, w1.y, acc[r].y);
            acc[r].z = fmaf(x.y, w1.z, acc[r].z); acc[r].w = fmaf(x.y, w1.w, acc[r].w);
            acc[r].x = fmaf(x.z, w2.x, acc[r].x); acc[r].y = fmaf(x.z, w2.y, acc[r].y);
            acc[r].z = fmaf(x.z, w2.z, acc[r].z); acc[r].w = fmaf(x.z, w2.w, acc[r].w);
            acc[r].x = fmaf(x.w, w3.x, acc[r].x); acc[r].y = fmaf(x.w, w3.y, acc[r].y);
            acc[r].z = fmaf(x.w, w3.z, acc[r].z); acc[r].w = fmaf(x.w, w3.w, acc[r].w);
        }
    }
    const float4 av = ((const float4*)avs)[col4];
    const float4 dv = ((const float4*)avd)[col4];
    #pragma unroll
    for (int r = 0; r < 8; ++r) {
        const int grow = row0 + rowg * 8 + r;
        if (grow < n) ((float4*)(S + (size_t)grow * 128))[col4] = acc[r];
        float ps = acc[r].x * av.x + acc[r].y * av.y + acc[r].z * av.z + acc[r].w * av.w;
        float pd = acc[r].x * dv.x + acc[r].y * dv.y + acc[r].z * dv.z + acc[r].w * dv.w;
        #pragma unroll
        for (int off = 8; off; off >>= 1) {  // reduce 16 col-lanes of this head
            ps += __shfl_xor(ps, off);
            pd += __shfl_xor(pd, off);
        }
        if ((col4 & 15) == 0 && grow < n) {
            const int h = col4 >> 4;
            as_[2 * grow + h] = ps;
            ad_[2 * grow + h] = pd;
        }
    }
}

// Per-dst softmax stats; materializes alpha[i] (float2 per csr slot).
// Fast path deg<=64: e kept in registers, single pass over memory.
__global__ __launch_bounds__(256) void gat_stats(
    const float* __restrict__ as_, const float* __restrict__ ad_,
    const int* __restrict__ rowp, const int* __restrict__ csr,
    float2* __restrict__ alpha, int n) {
    const int lane = threadIdx.x & 63;
    const int d = (blockIdx.x * blockDim.x + threadIdx.x) >> 6;
    if (d >= n) return;
    const int beg = rowp[d], end = rowp[d + 1];
    const float2 adv = *(const float2*)(ad_ + 2 * d);
    if (end - beg <= 64) {
        const int i = beg + lane;
        const bool has = i < end;
        float e0 = -1e30f, e1 = -1e30f;
        if (has) {
            const int s = csr[i];
            const float2 asv = *(const float2*)(as_ + 2 * s);
            e0 = asv.x + adv.x; e0 = e0 > 0.f ? e0 : 0.2f * e0;
            e1 = asv.y + adv.y; e1 = e1 > 0.f ? e1 : 0.2f * e1;
        }
        float m0 = e0, m1 = e1;
        #pragma unroll
        for (int off = 32; off; off >>= 1) {
            m0 = fmaxf(m0, __shfl_xor(m0, off));
            m1 = fmaxf(m1, __shfl_xor(m1, off));
        }
        float p0 = has ? __expf(e0 - m0) : 0.f;
        float p1 = has ? __expf(e1 - m1) : 0.f;
        float s0 = p0, s1 = p1;
        #pragma unroll
        for (int off = 32; off; off >>= 1) {
            s0 += __shfl_xor(s0, off);
            s1 += __shfl_xor(s1, off);
        }
        if (has) alpha[i] = make_float2(p0 / s0, p1 / s1);
    } else {
        float m0 = -1e30f, m1 = -1e30f;
        for (int i = beg + lane; i < end; i += 64) {
            const int s = csr[i];
            const float2 asv = *(const float2*)(as_ + 2 * s);
            float e0 = asv.x + adv.x; e0 = e0 > 0.f ? e0 : 0.2f * e0;
            float e1 = asv.y + adv.y; e1 = e1 > 0.f ? e1 : 0.2f * e1;
            m0 = fmaxf(m0, e0); m1 = fmaxf(m1, e1);
        }
        #pragma unroll
        for (int off = 32; off; off >>= 1) {
            m0 = fmaxf(m0, __shfl_xor(m0, off));
            m1 = fmaxf(m1, __shfl_xor(m1, off));
        }
        float s0 = 0.f, s1 = 0.f;
        for (int i = beg + lane; i < end; i += 64) {
            const int s = csr[i];
            const float2 asv = *(const float2*)(as_ + 2 * s);
            float e0 = asv.x + adv.x; e0 = e0 > 0.f ? e0 : 0.2f * e0;
            float e1 = asv.y + adv.y; e1 = e1 > 0.f ? e1 : 0.2f * e1;
            s0 += __expf(e0 - m0); s1 += __expf(e1 - m1);
        }
        #pragma unroll
        for (int off = 32; off; off >>= 1) {
            s0 += __shfl_xor(s0, off);
            s1 += __shfl_xor(s1, off);
        }
        const float r0 = 1.f / s0, r1 = 1.f / s1;
        for (int i = beg + lane; i < end; i += 64) {
            const int s = csr[i];
            const float2 asv = *(const float2*)(as_ + 2 * s);
            float e0 = asv.x + adv.x; e0 = e0 > 0.f ? e0 : 0.2f * e0;
            float e1 = asv.y + adv.y; e1 = e1 > 0.f ? e1 : 0.2f * e1;
            alpha[i] = make_float2(__expf(e0 - m0) * r0, __expf(e1 - m1) * r1);
        }
    }
}

// Weighted gather: one wave per dst; main loop 4 edges/iter (2 per half-wave,
// both 512B loads in flight), float4 per lane. No exp, no softmax.
// mode 0=ELU(concat), 1=ReLU(concat), 2=ReLU(head-mean).
__global__ __launch_bounds__(256) void gat_gather(
    const float* __restrict__ S, const float2* __restrict__ alpha,
    const int* __restrict__ rowp, const int* __restrict__ csr,
    const float* __restrict__ bias, float* __restrict__ out, int n, int mode) {
    const int lane = threadIdx.x & 63;
    const int d = (blockIdx.x * blockDim.x + threadIdx.x) >> 6;
    if (d >= n) return;
    const int beg = rowp[d], end = rowp[d + 1];
    const int half = lane >> 5;   // which edge of a pair
    const int c4 = lane & 31;     // float4 col group (head = c4>>4)
    const int head = c4 >> 4;
    float4 acc = make_float4(0.f, 0.f, 0.f, 0.f);
    int i = beg;
    for (; i + 4 <= end; i += 4) {
        const int j0 = i + half, j1 = i + 2 + half;
        const int sa = csr[j0], sb = csr[j1];
        const float2 a2a = alpha[j0], a2b = alpha[j1];
        const float aa = head ? a2a.y : a2a.x;
        const float ab = head ? a2b.y : a2b.x;
        const float4 va = ((const float4*)(S + ((size_t)sa << 7)))[c4];
        const float4 vb = ((const float4*)(S + ((size_t)sb << 7)))[c4];
        acc.x = fmaf(aa, va.x, acc.x); acc.y = fmaf(aa, va.y, acc.y);
        acc.z = fmaf(aa, va.z, acc.z); acc.w = fmaf(aa, va.w, acc.w);
        acc.x = fmaf(ab, vb.x, acc.x); acc.y = fmaf(ab, vb.y, acc.y);
        acc.z = fmaf(ab, vb.z, acc.z); acc.w = fmaf(ab, vb.w, acc.w);
    }
    for (; i < end; i += 2) {
        const int j = i + half;
        const bool valid = j < end;
        const int jj = valid ? j : i;
        const int s = csr[jj];
        const float2 a2 = alpha[jj];
        float a = head ? a2.y : a2.x;
        if (!valid) a = 0.f;
        const float4 v = ((const float4*)(S + ((size_t)s << 7)))[c4];
        acc.x = fmaf(a, v.x, acc.x);
        acc.y = fmaf(a, v.y, acc.y);
        acc.z = fmaf(a, v.z, acc.z);
        acc.w = fmaf(a, v.w, acc.w);
    }
    // combine even/odd edge halves (lane l and l+32 hold same col group)
    acc.x += __shfl_xor(acc.x, 32);
    acc.y += __shfl_xor(acc.y, 32);
    acc.z += __shfl_xor(acc.z, 32);
    acc.w += __shfl_xor(acc.w, 32);
    if (mode == 2) {
        // head-mean: lane c4<16 (head0 cols) pairs with c4+16 (head1 cols)
        float4 oth;
        oth.x = __shfl_xor(acc.x, 16);
        oth.y = __shfl_xor(acc.y, 16);
        oth.z = __shfl_xor(acc.z, 16);
        oth.w = __shfl_xor(acc.w, 16);
        if (lane < 16) {
            const float4 b = ((const float4*)bias)[c4];
            float4 o;
            o.x = fmaxf(0.5f * (acc.x + oth.x) + b.x, 0.f);
            o.y = fmaxf(0.5f * (acc.y + oth.y) + b.y, 0.f);
            o.z = fmaxf(0.5f * (acc.z + oth.z) + b.z, 0.f);
            o.w = fmaxf(0.5f * (acc.w + oth.w) + b.w, 0.f);
            ((float4*)(out + (size_t)d * 64))[c4] = o;
        }
    } else if (lane < 32) {
        const float4 b = ((const float4*)bias)[c4];
        float4 o;
        o.x = acc.x + b.x; o.y = acc.y + b.y; o.z = acc.z + b.z; o.w = acc.w + b.w;
        if (mode == 0) {
            o.x = o.x > 0.f ? o.x : expm1f(o.x);
            o.y = o.y > 0.f ? o.y : expm1f(o.y);
            o.z = o.z > 0.f ? o.z : expm1f(o.z);
            o.w = o.w > 0.f ? o.w : expm1f(o.w);
        } else {
            o.x = fmaxf(o.x, 0.f); o.y = fmaxf(o.y, 0.f);
            o.z = fmaxf(o.z, 0.f); o.w = fmaxf(o.w, 0.f);
        }
        ((float4*)(out + (size_t)d * 128))[c4] = o;
    }
}

extern "C" void kernel_launch(void* const* d_in, const int* in_sizes, int n_in,
                              void* d_out, int out_size, void* d_ws, size_t ws_size,
                              hipStream_t stream) {
    const float* X   = (const float*)d_in[0];
    const void*  EI  = d_in[1];
    const float* W0  = (const float*)d_in[2];
    const float* as0 = (const float*)d_in[3];
    const float* ad0 = (const float*)d_in[4];
    const float* b0  = (const float*)d_in[5];
    const float* W1  = (const float*)d_in[6];
    const float* as1 = (const float*)d_in[7];
    const float* ad1 = (const float*)d_in[8];
    const float* b1  = (const float*)d_in[9];
    const float* W2  = (const float*)d_in[10];
    const float* as2 = (const float*)d_in[11];
    const float* ad2 = (const float*)d_in[12];
    const float* b2  = (const float*)d_in[13];

    const int N  = in_sizes[0] / 128;   // 50000
    const int E  = in_sizes[1] / 2;     // 1600000
    const int ET = E + N;               // + self loops
    const int NB = (N + SCAN_BLOCK - 1) / SCAN_BLOCK;  // scan blocks (196)

    char* p = (char*)d_ws;
    size_t used = 0;
    auto alloc = [&](size_t bytes) -> void* {
        void* r = p + used;
        used += (bytes + 255) & ~(size_t)255;
        return r;
    };
    float*  S    = (float*)alloc((size_t)N * 128 * 4);
    float*  H0   = (float*)alloc((size_t)N * 128 * 4);
    float*  H1   = (float*)alloc((size_t)N * 128 * 4);
    int*    csr  = (int*)alloc((size_t)ET * 4);
    float2* alp  = (float2*)alloc((size_t)ET * 8);
    int*    rowp = (int*)alloc((size_t)(N + 1) * 4);
    int*    cnt  = (int*)alloc((size_t)N * 4);
    int*    part = (int*)alloc((size_t)N * 4);
    int*    bsum = (int*)alloc((size_t)NB * 4);
    float*  asb  = (float*)alloc((size_t)N * 2 * 4);
    float*  adb  = (float*)alloc((size_t)N * 2 * 4);
    int*    flag = (int*)alloc(256);
    if (used > ws_size) return;  // fail loudly (validation will catch)
    // rank aliases alpha: rank is dead before gat_stats first writes alpha.
    int* rank = (int*)alp;

    hipMemsetAsync(cnt, 0, (size_t)N * 4, stream);
    detect_i64<<<1, 64, 0, stream>>>((const unsigned*)EI, flag);
    gat_rank<<<2048, 256, 0, stream>>>(EI, flag, E, N, cnt, rank);
    scan_stage1<<<NB, SCAN_BLOCK, 0, stream>>>(cnt, part, bsum, N);
    scan_stage2<<<1, 64, 0, stream>>>(bsum, NB, rowp, N);
    scan_stage3<<<NB, SCAN_BLOCK, 0, stream>>>(part, cnt, bsum, rowp, N);
    gat_place<<<2048, 256, 0, stream>>>(EI, flag, E, N, rowp, rank, csr);

    const int gemm_blocks = (N + 63) / 64;
    const int wave_blocks = (N + 3) / 4;  // 4 waves/block, 1 dst/wave

    // layer 0: GATConv(128 -> 64, H=2, concat) + ELU
    gemm_alpha<<<gemm_blocks, 256, 0, stream>>>(X, W0, as0, ad0, S, asb, adb, N);
    gat_stats<<<wave_blocks, 256, 0, stream>>>(asb, adb, rowp, csr, alp, N);
    gat_gather<<<wave_blocks, 256, 0, stream>>>(S, alp, rowp, csr, b0, H0, N, 0);
    // layer 1: GATConv(128 -> 64, H=2, concat) + ReLU
    gemm_alpha<<<gemm_blocks, 256, 0, stream>>>(H0, W1, as1, ad1, S, asb, adb, N);
    gat_stats<<<wave_blocks, 256, 0, stream>>>(asb, adb, rowp, csr, alp, N);
    gat_gather<<<wave_blocks, 256, 0, stream>>>(S, alp, rowp, csr, b1, H1, N, 1);
    // layer 2: GATConvMean(128 -> 64, H=2, mean) + ReLU
    gemm_alpha<<<gemm_blocks, 256, 0, stream>>>(H1, W2, as2, ad2, S, asb, adb, N);
    gat_stats<<<wave_blocks, 256, 0, stream>>>(asb, adb, rowp, csr, alp, N);
    gat_gather<<<wave_blocks, 256, 0, stream>>>(S, alp, rowp, csr, b2, (float*)d_out, N, 2);
}